// Round 11
// baseline (178.363 us; speedup 1.0000x reference)
//
#include <hip/hip_runtime.h>
#include <stdint.h>

#define B_ 64
#define T_ 4096
#define D_ 90
#define K_ 32
#define CH_ 32   // chunk length (one wave = one chunk, split into 2 half-chains)
#define F_  128  // chunks per b
#define NB_ 2048 // fused blocks (128 t each, 4 chunks composed in-block)

typedef float f32x16 __attribute__((ext_vector_type(16)));
typedef float f32x2  __attribute__((ext_vector_type(2)));
typedef __bf16 bf16x8 __attribute__((ext_vector_type(8)));

// ---- workspace layout (float offsets). total ~4.3 MB ----
#define WS_A     0          // 1024 : softmax(transition) rows, A[j*32+k]
#define WS_PI    1024       // 32   : softmax(priors)
#define WS_C0    1056       // 32   : per-state emission constant
#define WS_WF    1088       // 6144 bf16 : MFMA B-fragments of emission weights
#define WS_EACC  4160       // 2048 ints : per-block renorm exponent
#define WS_MS    12352      // 2048 : per-block msum
#define WS_E0    20544      // 2048 bf16 : E[b][k][t=0] for the alpha0 term
#define WS_Q2    22080      // 2097152 bf16 : per-block composed products

// LDS (ushort offsets):
//   [0, 5120)        : 4 per-wave regions of 1280 (X staging 768 -> E tile -> Q)
//   [5120, 11264)    : WF weight fragments [cm][lane], 16B per lane
#define LDS_WREG(w) ((w) * 1280)
#define LDS_WF      5120
#define LDS_TOT     11264

// block-swap involution: swap 4-7<->8-11 and 20-23<->24-27
__device__ __forceinline__ int perm_r(int r) {
  int t2 = (r >> 2) & 3;
  return r + ((t2 == 1) ? 4 : (t2 == 2) ? -4 : 0);
}
// pack two f32 -> bf16x2 dword, truncation — single v_perm_b32
__device__ __forceinline__ uint32_t pk2(float hi, float lo) {
  return __builtin_amdgcn_perm(__float_as_uint(hi), __float_as_uint(lo), 0x07060302u);
}
// round-to-nearest variant (emission path)
__device__ __forceinline__ uint32_t rnd_pk(float hi, float lo) {
  uint32_t uh = __float_as_uint(hi) + 0x8000u;
  uint32_t ul = __float_as_uint(lo) + 0x8000u;
  return __builtin_amdgcn_perm(uh, ul, 0x07060302u);
}
__device__ __forceinline__ float bf2f(ushort u) {
  return __uint_as_float(((uint32_t)u) << 16);
}
__device__ __forceinline__ bf16x8 mkbf(uint32_t a, uint32_t b, uint32_t c, uint32_t d) {
  union { uint32_t u[4]; bf16x8 v; } x;
  x.u[0] = a; x.u[1] = b; x.u[2] = c; x.u[3] = d;
  return x.v;
}

// ---------------- prep: softmaxes + emission weight fragments ----------------
__global__ __launch_bounds__(1024) void prep_kernel(
    const float* __restrict__ priors, const float* __restrict__ trans,
    const float* __restrict__ mu, const float* __restrict__ lv,
    float* __restrict__ ws) {
  int tid = threadIdx.x;
  {  // transition row softmax: tid = j*32+k, 32-lane groups are rows
    float v = trans[tid];
    float m = v;
    #pragma unroll
    for (int mk = 16; mk; mk >>= 1) m = fmaxf(m, __shfl_xor(m, mk));
    float e = expf(v - m);
    float s = e;
    #pragma unroll
    for (int mk = 16; mk; mk >>= 1) s += __shfl_xor(s, mk);
    ws[WS_A + tid] = e / s;
  }
  if (tid < 32) {  // prior softmax
    float v = priors[tid];
    float m = v;
    #pragma unroll
    for (int mk = 16; mk; mk >>= 1) m = fmaxf(m, __shfl_xor(m, mk));
    float e = expf(v - m);
    float s = e;
    #pragma unroll
    for (int mk = 16; mk; mk >>= 1) s += __shfl_xor(s, mk);
    ws[WS_PI + tid] = e / s;
  }
  // MFMA B-operand weight fragments, bf16, layout [c][mat][lane][j]
  for (int i = tid; i < 6144; i += 1024) {
    int j = i & 7, l = (i >> 3) & 63, cm = i >> 9;
    int c = cm >> 1, mat = cm & 1;
    int h = l >> 5, nn = l & 31;
    int d = 16 * c + 8 * h + j;
    float v = 0.0f;
    if (d < D_) {
      float ivd = expf(-lv[nn * D_ + d]);
      v = (mat == 0) ? -0.5f * ivd : mu[nn * D_ + d] * ivd;
    }
    ((ushort*)(ws + WS_WF))[i] = (ushort)((__float_as_uint(v) + 0x8000u) >> 16);
  }
  {  // c0[k], parallel: 32 lanes per state, shfl-reduced
    int nn = tid >> 5, j = tid & 31;
    float s = 0.0f;
    for (int d = j; d < D_; d += 32) {
      float lvv = lv[nn * D_ + d];
      float iv  = expf(-lvv);
      float m_  = mu[nn * D_ + d];
      s += m_ * m_ * iv + lvv;
    }
    #pragma unroll
    for (int mk = 16; mk; mk >>= 1) s += __shfl_xor(s, mk);
    if (j == 0) ws[WS_C0 + nn] = -0.5f * (s + (float)D_ * 1.8378770664093453f);
  }
}

// ---------------- fused: staged emission -> E in LDS -> TWO interleaved
//                  16-step half-chains -> in-wave merge -> in-block compose ----
// Block = 128 t of one b; wave w owns one 32-t chunk. The chunk's 32-step serial
// MFMA chain is split by associativity: Q_lo = M15..M0, Q_hi = M31..M16, run
// interleaved (independent states, shared astat, SAME E tile -> zero extra LDS),
// merged with one lmul via the wave's LDS region. Chain length 32 -> 16+1.
// (256,6): cap ~85, 6 blocks/CU — R6-proven no-spill at this LDS (22.6 KB).
__global__ __launch_bounds__(256, 6) void fused_kernel(const float* __restrict__ X,
                                                       float* __restrict__ ws,
                                                       float* __restrict__ out) {
  __shared__ __align__(16) ushort sh[LDS_TOT];
  __shared__ float msb[4];
  __shared__ int   peb[4];
  int tid = threadIdx.x;
  int l = tid & 63, w = tid >> 6;
  int n = l & 31, h = l >> 5;
  int tB = blockIdx.x << 7;
  int t0 = tB + (w << 5);
  int b  = t0 >> 12;
  if (blockIdx.x == 0 && tid == 0) *out = 0.0f;   // stream-ordered before combine

  // ---- stage WF table into LDS (once per block): 768 uint4 ----
  {
    const uint4* wfp = (const uint4*)((const ushort*)(ws + WS_WF));
    uint4* wfl = (uint4*)(sh + LDS_WF);
    #pragma unroll
    for (int k = 0; k < 3; ++k) wfl[tid + (k << 8)] = wfp[tid + (k << 8)];
  }
  float c0 = ws[WS_C0 + n];

  // ---- per-wave X slice staging: lane covers (row = l>>1, half sp = l&1) ----
  int srow = l >> 1, sp = l & 1;
  const float* xg = X + (size_t)(t0 + srow) * D_ + 8 * sp;
  ushort* xbuf = sh + LDS_WREG(w);        // first 768 ushorts of the wave region
  float2 va[4];
  auto xload = [&](int c) {
    #pragma unroll
    for (int s = 0; s < 4; ++s) {
      int d = 16 * c + 8 * sp + 2 * s;
      if (d < D_) va[s] = *(const float2*)(xg + 16 * c + 2 * s);
      else { va[s].x = 0.0f; va[s].y = 0.0f; }
    }
  };
  auto xwrite = [&]() {
    uint4 pkv;
    pkv.x = rnd_pk(va[0].y, va[0].x);
    pkv.y = rnd_pk(va[1].y, va[1].x);
    pkv.z = rnd_pk(va[2].y, va[2].x);
    pkv.w = rnd_pk(va[3].y, va[3].x);
    *(uint4*)(xbuf + srow * 24 + 8 * sp) = pkv;   // 16B-aligned (stride 48B)
  };
  xload(0);
  xwrite();          // slice 0 in LDS
  xload(1);          // slice 1 pending in regs
  __syncthreads();   // barrier#1: WF table ready

  // ---- emission: single accumulator, x*W1 + x^2*W2 ----
  const ushort* wfl = sh + LDS_WF;
  f32x16 acc;
  #pragma unroll
  for (int r = 0; r < 16; ++r) acc[r] = 0.0f;
  #pragma unroll
  for (int c = 0; c < 6; ++c) {
    union { uint4 u; bf16x8 v; } xb;
    xb.u = *(const uint4*)(xbuf + n * 24 + 8 * h);   // A-frag, slice c
    float x[8];
    #pragma unroll
    for (int j = 0; j < 8; ++j) {
      uint32_t uu = ((const uint32_t*)&xb.u)[j >> 1];
      x[j] = bf2f((j & 1) ? (ushort)(uu >> 16) : (ushort)(uu & 0xFFFF));
    }
    union { uint32_t u[4]; bf16x8 v; } x2b;
    #pragma unroll
    for (int r = 0; r < 4; ++r) {
      f32x2 xv = { x[2*r], x[2*r+1] };
      f32x2 xs = xv * xv;                 // v_pk_mul_f32 candidate
      x2b.u[r] = rnd_pk(xs[1], xs[0]);
    }
    union { uint4 u; bf16x8 v; } w1, w2;
    w2.u = *(const uint4*)(wfl + (2 * c)     * 512 + l * 8);   // -0.5*iv
    w1.u = *(const uint4*)(wfl + (2 * c + 1) * 512 + l * 8);   // mu*iv
    acc = __builtin_amdgcn_mfma_f32_32x32x16_bf16(xb.v,  w1.v, acc, 0, 0, 0);
    acc = __builtin_amdgcn_mfma_f32_32x32x16_bf16(x2b.v, w2.v, acc, 0, 0, 0);
    if (c < 5) {
      xwrite();                 // write pending slice (DS order after read)
      if (c < 4) xload(c + 2);  // prefetch next into regs
    }
  }
  // C/D: col k = n, row t = (r&3) + 8*(r>>2) + 4*h
  float em[16], mrow[16];
  #pragma unroll
  for (int r = 0; r < 16; ++r) {
    float v = acc[r] + c0;
    em[r] = v;
    float m = v;
    #pragma unroll
    for (int mk = 1; mk <= 16; mk <<= 1) m = fmaxf(m, __shfl_xor(m, mk));  // max over k
    mrow[r] = m;
  }
  // E[k=n][t] tile, stride 40, overlays the (now dead) X buf of this wave.
  ushort* Ew = sh + LDS_WREG(w);
  #pragma unroll
  for (int q = 0; q < 4; ++q) {
    float e0 = exp2f((em[4*q]   - mrow[4*q])   * 1.44269504088896f);
    float e1 = exp2f((em[4*q+1] - mrow[4*q+1]) * 1.44269504088896f);
    float e2 = exp2f((em[4*q+2] - mrow[4*q+2]) * 1.44269504088896f);
    float e3 = exp2f((em[4*q+3] - mrow[4*q+3]) * 1.44269504088896f);
    uint2 d;
    d.x = rnd_pk(e1, e0);
    d.y = rnd_pk(e3, e2);
    *(uint2*)(Ew + n * 40 + 8 * q + 4 * h) = d;
    if (q == 0 && h == 0 && (t0 & (T_ - 1)) == 0)   // export E[b][k][0] for alpha0
      ((ushort*)(ws + WS_E0))[b * K_ + n] = (ushort)(d.x & 0xFFFF);
  }
  float msum = 0.0f;
  #pragma unroll
  for (int r = 0; r < 16; ++r) msum += mrow[r];
  msum += __shfl_xor(msum, 32);
  if (l == 0) msb[w] = msum;
  // no barrier: E tile is wave-private, in-wave lgkm ordering suffices

  // ---- two interleaved 16-step half-chains over the SAME E tile ----
  int col = perm_r(n);                    // logical output-state of this lane's A column
  const float* A = ws + WS_A;
  f32x2 astat2[8];                        // pairs (rows 8h+2r, +1) and (+16)
  #pragma unroll
  for (int r = 0; r < 4; ++r) {
    astat2[r]     = f32x2{ A[(8 * h + 2 * r) * K_ + col],
                           A[(8 * h + 2 * r + 1) * K_ + col] };
    astat2[4 + r] = f32x2{ A[(16 + 8 * h + 2 * r) * K_ + col],
                           A[(16 + 8 * h + 2 * r + 1) * K_ + col] };
  }
  int eacc = 0;                           // shared exponent accumulator (sum commutes)
  const f32x16 z = {0.f,0.f,0.f,0.f,0.f,0.f,0.f,0.f,0.f,0.f,0.f,0.f,0.f,0.f,0.f,0.f};
  f32x16 accA, accB;
  uint32_t qA[8], qB[8];
  #pragma unroll
  for (int r = 0; r < 16; ++r) { accA[r] = 0.0f; accB[r] = 0.0f; }
  #pragma unroll
  for (int r = 0; r < 4; ++r) {           // both B-frags = identity
    int s0 = 8 * h + 2 * r;
    uint32_t lo = (s0 == n)     ? 0x3F80u : 0u;
    uint32_t hi = (s0 + 1 == n) ? 0x3F80u : 0u;
    qA[r] = lo | (hi << 16);  qB[r] = qA[r];
    int s2 = s0 + 16;
    lo = (s2 == n)     ? 0x3F80u : 0u;
    hi = (s2 + 1 == n) ? 0x3F80u : 0u;
    qA[4 + r] = lo | (hi << 16);  qB[4 + r] = qA[4 + r];
  }

  auto stepc = [&](f32x16& acc_, uint32_t (&q_)[8], float e0) {
    uint32_t au[8];
    #pragma unroll
    for (int r = 0; r < 4; ++r) {         // A-frag = astat * E[col]; pk_mul + perm
      f32x2 p0 = astat2[r] * e0;
      f32x2 p1 = astat2[4 + r] * e0;
      au[r]     = pk2(p0[1], p0[0]);
      au[4 + r] = pk2(p1[1], p1[0]);
    }
    bf16x8 alo = mkbf(au[0], au[1], au[2], au[3]);
    bf16x8 ahi = mkbf(au[4], au[5], au[6], au[7]);
    bf16x8 qlo = mkbf(q_[0], q_[1], q_[2], q_[3]);
    bf16x8 qhi = mkbf(q_[4], q_[5], q_[6], q_[7]);
    acc_ = __builtin_amdgcn_mfma_f32_32x32x16_bf16(alo, qlo, z, 0, 0, 0);
    acc_ = __builtin_amdgcn_mfma_f32_32x32x16_bf16(ahi, qhi, acc_, 0, 0, 0);
    #pragma unroll
    for (int r = 0; r < 4; ++r) {         // D regs -> next B-frag, in-lane repack
      q_[r]     = pk2(acc_[2 * r + 1], acc_[2 * r]);
      q_[4 + r] = pk2(acc_[8 + 2 * r + 1], acc_[8 + 2 * r]);
    }
  };
  auto lmulc = [&](f32x16& acc_, uint32_t (&q_)[8], uint4 lo, uint4 hi) {
    bf16x8 alo = mkbf(lo.x, lo.y, lo.z, lo.w);
    bf16x8 ahi = mkbf(hi.x, hi.y, hi.z, hi.w);
    bf16x8 qlo = mkbf(q_[0], q_[1], q_[2], q_[3]);
    bf16x8 qhi = mkbf(q_[4], q_[5], q_[6], q_[7]);
    acc_ = __builtin_amdgcn_mfma_f32_32x32x16_bf16(alo, qlo, z, 0, 0, 0);
    acc_ = __builtin_amdgcn_mfma_f32_32x32x16_bf16(ahi, qhi, acc_, 0, 0, 0);
    #pragma unroll
    for (int r = 0; r < 4; ++r) {
      q_[r]     = pk2(acc_[2 * r + 1], acc_[2 * r]);
      q_[4 + r] = pk2(acc_[8 + 2 * r + 1], acc_[8 + 2 * r]);
    }
  };
  auto renormc = [&](f32x16& acc_, uint32_t (&q_)[8]) {  // exact pow-2 renorm
    float m = acc_[0];
    #pragma unroll
    for (int r = 1; r < 16; ++r) m = fmaxf(m, acc_[r]);
    #pragma unroll
    for (int mk = 1; mk <= 32; mk <<= 1) m = fmaxf(m, __shfl_xor(m, mk));
    int ex;
    frexpf(m, &ex);
    float sc = ldexpf(1.0f, -ex);
    eacc += ex;
    #pragma unroll
    for (int r = 0; r < 16; ++r) acc_[r] *= sc;
    #pragma unroll
    for (int r = 0; r < 4; ++r) {
      q_[r]     = pk2(acc_[2 * r + 1], acc_[2 * r]);
      q_[4 + r] = pk2(acc_[8 + 2 * r + 1], acc_[8 + 2 * r]);
    }
  };

  const ushort* Eb = sh + LDS_WREG(w) + col * 40;
  bool first = ((t0 & (T_ - 1)) == 0);
  #pragma unroll
  for (int g = 0; g < 2; ++g) {           // chain A: groups g; chain B: groups g+2
    uint4 evA = *(const uint4*)(Eb + 8 * g);
    uint4 evB = *(const uint4*)(Eb + 8 * (g + 2));
    #pragma unroll
    for (int j = 0; j < 8; ++j) {
      uint32_t uA = ((const uint32_t*)&evA)[j >> 1];
      uint32_t uB = ((const uint32_t*)&evB)[j >> 1];
      float eA = bf2f((j & 1) ? (ushort)(uA >> 16) : (ushort)(uA & 0xFFFF));
      float eB = bf2f((j & 1) ? (ushort)(uB >> 16) : (ushort)(uB & 0xFFFF));
      if (g == 0 && j == 0) {             // t=0 is the prior step for chunk 0: skip
        if (!first) stepc(accA, qA, eA);
      } else {
        stepc(accA, qA, eA);
      }
      stepc(accB, qB, eB);                // independent chain — interleaves with A
    }
    renormc(accA, qA);
    renormc(accB, qB);
  }

  // ---- in-wave merge: Q_chunk = Q_hi (chain B) x Q_lo (chain A) ----
  // publish chain B's product into own (fully consumed) E region, perm'd rows,
  // then read it back as A-frags and left-multiply onto chain A's state.
  ushort* Qw = sh + LDS_WREG(w);          // 32 rows x stride 40
  #pragma unroll
  for (int r = 0; r < 16; ++r) {
    int m_ = (r & 3) + 8 * (r >> 2) + 4 * h;
    Qw[perm_r(m_) * 40 + n] = (ushort)(__float_as_uint(accB[r]) >> 16);
  }
  {
    const ushort* baseB = sh + LDS_WREG(w) + col * 40;  // in-wave DS order: safe
    uint4 lo = *(const uint4*)(baseB + 8 * h);
    uint4 hi = *(const uint4*)(baseB + 16 + 8 * h);
    lmulc(accA, qA, lo, hi);
  }
  renormc(accA, qA);

  // publish chunk product into own wave region (overwrite, wave-private)
  #pragma unroll
  for (int r = 0; r < 16; ++r) {          // row = pi(physical row), col = n
    int m_ = (r & 3) + 8 * (r >> 2) + 4 * h;
    Qw[perm_r(m_) * 40 + n] = (ushort)(__float_as_uint(accA[r]) >> 16);
  }
  if (l == 0) peb[w] = eacc;
  __syncthreads();                        // barrier#2: all Q products published
  if (w != 0) return;

  // ---- wave 0: compose the 4 chunk products (ascending = later on the left) ----
  #pragma unroll
  for (int r = 0; r < 4; ++r) {           // reset B-frag to identity
    int s0 = 8 * h + 2 * r;
    uint32_t lo = (s0 == n)     ? 0x3F80u : 0u;
    uint32_t hi = (s0 + 1 == n) ? 0x3F80u : 0u;
    qA[r] = lo | (hi << 16);
    int s2 = s0 + 16;
    lo = (s2 == n)     ? 0x3F80u : 0u;
    hi = (s2 + 1 == n) ? 0x3F80u : 0u;
    qA[4 + r] = lo | (hi << 16);
  }
  eacc = peb[0] + peb[1] + peb[2] + peb[3];
  float msm = msb[0] + msb[1] + msb[2] + msb[3];
  #pragma unroll
  for (int r = 0; r < 16; ++r) accA[r] = 0.0f;
  #pragma unroll
  for (int p = 0; p < 4; ++p) {
    const ushort* base = sh + LDS_WREG(p) + col * 40;  // col == A-frag row
    uint4 lo = *(const uint4*)(base + 8 * h);
    uint4 hi = *(const uint4*)(base + 16 + 8 * h);
    lmulc(accA, qA, lo, hi);
  }
  renormc(accA, qA);
  ushort* Qo = (ushort*)(ws + WS_Q2) + (size_t)blockIdx.x * (K_ * K_);
  #pragma unroll
  for (int r = 0; r < 16; ++r) {
    int m_ = (r & 3) + 8 * (r >> 2) + 4 * h;
    Qo[perm_r(m_) * K_ + n] = (ushort)(__float_as_uint(accA[r]) >> 16);
  }
  if (l == 0) {
    ((int*)ws)[WS_EACC + blockIdx.x] = eacc;
    ws[WS_MS + blockIdx.x] = msm;
  }
}

// ---------------- combine: per b, compose 32 block products + alpha0 ----------------
__global__ __launch_bounds__(256) void combine_kernel(float* __restrict__ ws,
                                                      float* __restrict__ out) {
  __shared__ __align__(16) ushort pm[4][1280];   // stage-1 partials, stride 40
  __shared__ int pe[4];
  int tid = threadIdx.x;
  int l = tid & 63, w = tid >> 6;
  int h = l >> 5, n = l & 31;
  int b = blockIdx.x;
  int row = perm_r(n);
  int eacc;
  {
    const int* ea = ((const int*)ws) + WS_EACC + b * 32 + w * 8;
    int v = (l < 8) ? ea[l] : 0;
    #pragma unroll
    for (int mk = 1; mk <= 4; mk <<= 1) v += __shfl_xor(v, mk);
    eacc = __shfl(v, 0);
  }
  uint32_t q[8];                          // B-frag = identity
  #pragma unroll
  for (int r = 0; r < 4; ++r) {
    int s0 = 8 * h + 2 * r;
    uint32_t lo = (s0 == n)     ? 0x3F80u : 0u;
    uint32_t hi = (s0 + 1 == n) ? 0x3F80u : 0u;
    q[r] = lo | (hi << 16);
    int s2 = s0 + 16;
    lo = (s2 == n)     ? 0x3F80u : 0u;
    hi = (s2 + 1 == n) ? 0x3F80u : 0u;
    q[4 + r] = lo | (hi << 16);
  }
  f32x16 acc;
  #pragma unroll
  for (int r = 0; r < 16; ++r) acc[r] = 0.0f;
  const f32x16 z = {0.f,0.f,0.f,0.f,0.f,0.f,0.f,0.f,0.f,0.f,0.f,0.f,0.f,0.f,0.f,0.f};

  auto lmul = [&](uint4 lo, uint4 hi) {
    bf16x8 alo = mkbf(lo.x, lo.y, lo.z, lo.w);
    bf16x8 ahi = mkbf(hi.x, hi.y, hi.z, hi.w);
    bf16x8 qlo = mkbf(q[0], q[1], q[2], q[3]);
    bf16x8 qhi = mkbf(q[4], q[5], q[6], q[7]);
    acc = __builtin_amdgcn_mfma_f32_32x32x16_bf16(alo, qlo, z, 0, 0, 0);
    acc = __builtin_amdgcn_mfma_f32_32x32x16_bf16(ahi, qhi, acc, 0, 0, 0);
    #pragma unroll
    for (int r = 0; r < 4; ++r) {
      q[r]     = pk2(acc[2 * r + 1], acc[2 * r]);
      q[4 + r] = pk2(acc[8 + 2 * r + 1], acc[8 + 2 * r]);
    }
  };
  auto renorm = [&]() {
    float m = acc[0];
    #pragma unroll
    for (int r = 1; r < 16; ++r) m = fmaxf(m, acc[r]);
    #pragma unroll
    for (int mk = 1; mk <= 32; mk <<= 1) m = fmaxf(m, __shfl_xor(m, mk));
    int ex;
    frexpf(m, &ex);
    float sc = ldexpf(1.0f, -ex);
    eacc += ex;
    #pragma unroll
    for (int r = 0; r < 16; ++r) acc[r] *= sc;
    #pragma unroll
    for (int r = 0; r < 4; ++r) {
      q[r]     = pk2(acc[2 * r + 1], acc[2 * r]);
      q[4 + r] = pk2(acc[8 + 2 * r + 1], acc[8 + 2 * r]);
    }
  };

  // stage 1: wave w composes block products v = 8w .. 8w+7 (ascending)
  const ushort* Qb = (const ushort*)(ws + WS_Q2) + (size_t)(b * 32 + w * 8) * (K_ * K_);
  #pragma unroll
  for (int p = 0; p < 8; ++p) {
    const ushort* Mc = Qb + (size_t)p * (K_ * K_) + row * K_;
    uint4 lo = *(const uint4*)(Mc + 8 * h);
    uint4 hi = *(const uint4*)(Mc + 16 + 8 * h);
    lmul(lo, hi);
    if ((p & 3) == 3) renorm();
  }
  #pragma unroll
  for (int r = 0; r < 16; ++r) {
    int m_ = (r & 3) + 8 * (r >> 2) + 4 * h;
    pm[w][perm_r(m_) * 40 + n] = (ushort)(__float_as_uint(acc[r]) >> 16);
  }
  if (l == 0) pe[w] = eacc;
  __syncthreads();
  if (w != 0) return;

  // stage 2 (wave 0): compose 4 partials, apply alpha0, reduce, accumulate
  float alpha0 = ws[WS_PI + n] * bf2f(((const ushort*)(ws + WS_E0))[b * K_ + n]);
  float msm;
  {
    float v = (l < 32) ? ws[WS_MS + b * 32 + l] : 0.0f;
    #pragma unroll
    for (int mk = 1; mk <= 32; mk <<= 1) v += __shfl_xor(v, mk);
    msm = v;
  }
  #pragma unroll
  for (int r = 0; r < 4; ++r) {           // reset identity
    int s0 = 8 * h + 2 * r;
    uint32_t lo = (s0 == n)     ? 0x3F80u : 0u;
    uint32_t hi = (s0 + 1 == n) ? 0x3F80u : 0u;
    q[r] = lo | (hi << 16);
    int s2 = s0 + 16;
    lo = (s2 == n)     ? 0x3F80u : 0u;
    hi = (s2 + 1 == n) ? 0x3F80u : 0u;
    q[4 + r] = lo | (hi << 16);
  }
  #pragma unroll
  for (int r = 0; r < 16; ++r) acc[r] = 0.0f;
  int et = pe[0] + pe[1] + pe[2] + pe[3];
  #pragma unroll
  for (int p = 0; p < 4; ++p) {           // no renorm: entries bounded, fp32-safe
    const ushort* base = pm[p] + row * 40;
    uint4 lo = *(const uint4*)(base + 8 * h);
    uint4 hi = *(const uint4*)(base + 16 + 8 * h);
    lmul(lo, hi);
  }
  // ssum = sum_{k,j} Qtot[k][j] * alpha0[j]; lane holds col n, rows across (r,h)
  float part = 0.0f;
  #pragma unroll
  for (int r = 0; r < 16; ++r) part += acc[r];
  part *= alpha0;
  #pragma unroll
  for (int mk = 1; mk <= 32; mk <<= 1) part += __shfl_xor(part, mk);
  if (l == 0) {
    float res = logf(part) + (float)et * 0.69314718055994531f + msm;
    atomicAdd(out, res);
  }
}

extern "C" void kernel_launch(void* const* d_in, const int* in_sizes, int n_in,
                              void* d_out, int out_size, void* d_ws, size_t ws_size,
                              hipStream_t stream) {
  (void)in_sizes; (void)n_in; (void)out_size; (void)ws_size;
  const float* X      = (const float*)d_in[0];
  const float* priors = (const float*)d_in[1];
  const float* trans  = (const float*)d_in[2];
  const float* mu     = (const float*)d_in[3];
  const float* lv     = (const float*)d_in[4];
  float* ws  = (float*)d_ws;
  float* out = (float*)d_out;
  prep_kernel<<<1, 1024, 0, stream>>>(priors, trans, mu, lv, ws);
  fused_kernel<<<NB_, 256, 0, stream>>>(X, ws, out);
  combine_kernel<<<B_, 256, 0, stream>>>(ws, out);
}

// Round 12
// 174.528 us; speedup vs baseline: 1.0220x; 1.0220x over previous
//
#include <hip/hip_runtime.h>
#include <stdint.h>

#define B_ 64
#define T_ 4096
#define D_ 90
#define K_ 32
#define CH_ 32   // chunk length (one wave = one chunk)
#define F_  128  // chunks per b
#define NB_ 2048 // fused blocks (128 t each, 4 chunks composed in-block)

typedef float f32x16 __attribute__((ext_vector_type(16)));
typedef __bf16 bf16x8 __attribute__((ext_vector_type(8)));

// ---- workspace layout (float offsets). total ~4.3 MB ----
#define WS_A     0          // 1024 : softmax(transition) rows, A[j*32+k]
#define WS_PI    1024       // 32   : softmax(priors)
#define WS_C0    1056       // 32   : per-state emission constant
#define WS_WF    1088       // 6144 bf16 : MFMA B-fragments of emission weights
#define WS_EACC  4160       // 2048 ints : per-block renorm exponent
#define WS_MS    12352      // 2048 : per-block msum
#define WS_E0    20544      // 2048 bf16 : E[b][k][t=0] for the alpha0 term
#define WS_Q2    22080      // 2097152 bf16 : per-block composed products

// LDS (ushort offsets):
//   [0, 5120)        : 4 per-wave regions of 1280 (X staging 768 -> E tile -> Q product)
//   [5120, 11264)    : WF weight fragments [cm][lane], 16B per lane
#define LDS_WREG(w) ((w) * 1280)
#define LDS_WF      5120
#define LDS_TOT     11264

// block-swap involution: swap 4-7<->8-11 and 20-23<->24-27
__device__ __forceinline__ int perm_r(int r) {
  int t2 = (r >> 2) & 3;
  return r + ((t2 == 1) ? 4 : (t2 == 2) ? -4 : 0);
}
// pack two f32 -> bf16x2 dword, truncation — single v_perm_b32
__device__ __forceinline__ uint32_t pk2(float hi, float lo) {
  return __builtin_amdgcn_perm(__float_as_uint(hi), __float_as_uint(lo), 0x07060302u);
}
// round-to-nearest variant (emission path)
__device__ __forceinline__ uint32_t rnd_pk(float hi, float lo) {
  uint32_t uh = __float_as_uint(hi) + 0x8000u;
  uint32_t ul = __float_as_uint(lo) + 0x8000u;
  return __builtin_amdgcn_perm(uh, ul, 0x07060302u);
}
__device__ __forceinline__ float bf2f(ushort u) {
  return __uint_as_float(((uint32_t)u) << 16);
}
__device__ __forceinline__ bf16x8 mkbf(uint32_t a, uint32_t b, uint32_t c, uint32_t d) {
  union { uint32_t u[4]; bf16x8 v; } x;
  x.u[0] = a; x.u[1] = b; x.u[2] = c; x.u[3] = d;
  return x.v;
}

// ---------------- prep: softmaxes + emission weight fragments ----------------
__global__ __launch_bounds__(1024) void prep_kernel(
    const float* __restrict__ priors, const float* __restrict__ trans,
    const float* __restrict__ mu, const float* __restrict__ lv,
    float* __restrict__ ws) {
  int tid = threadIdx.x;
  {  // transition row softmax: tid = j*32+k, 32-lane groups are rows
    float v = trans[tid];
    float m = v;
    #pragma unroll
    for (int mk = 16; mk; mk >>= 1) m = fmaxf(m, __shfl_xor(m, mk));
    float e = expf(v - m);
    float s = e;
    #pragma unroll
    for (int mk = 16; mk; mk >>= 1) s += __shfl_xor(s, mk);
    ws[WS_A + tid] = e / s;
  }
  if (tid < 32) {  // prior softmax
    float v = priors[tid];
    float m = v;
    #pragma unroll
    for (int mk = 16; mk; mk >>= 1) m = fmaxf(m, __shfl_xor(m, mk));
    float e = expf(v - m);
    float s = e;
    #pragma unroll
    for (int mk = 16; mk; mk >>= 1) s += __shfl_xor(s, mk);
    ws[WS_PI + tid] = e / s;
  }
  // MFMA B-operand weight fragments, bf16, layout [c][mat][lane][j]
  for (int i = tid; i < 6144; i += 1024) {
    int j = i & 7, l = (i >> 3) & 63, cm = i >> 9;
    int c = cm >> 1, mat = cm & 1;
    int h = l >> 5, nn = l & 31;
    int d = 16 * c + 8 * h + j;
    float v = 0.0f;
    if (d < D_) {
      float ivd = expf(-lv[nn * D_ + d]);
      v = (mat == 0) ? -0.5f * ivd : mu[nn * D_ + d] * ivd;
    }
    ((ushort*)(ws + WS_WF))[i] = (ushort)((__float_as_uint(v) + 0x8000u) >> 16);
  }
  {  // c0[k], parallel: 32 lanes per state, shfl-reduced
    int nn = tid >> 5, j = tid & 31;
    float s = 0.0f;
    for (int d = j; d < D_; d += 32) {
      float lvv = lv[nn * D_ + d];
      float iv  = expf(-lvv);
      float m_  = mu[nn * D_ + d];
      s += m_ * m_ * iv + lvv;
    }
    #pragma unroll
    for (int mk = 16; mk; mk >>= 1) s += __shfl_xor(s, mk);
    if (j == 0) ws[WS_C0 + nn] = -0.5f * (s + (float)D_ * 1.8378770664093453f);
  }
}

// ---------------- fused: staged emission -> E in LDS -> recursion -> compose ----
// R6 structure (the measured optimum) with ONE change: the recursion step's two
// MFMAs are made INDEPENDENT (both accumulate from zero, D tiles summed with
// VALU adds) instead of serially chained through the C operand. Critical path
// per step: 2x MFMA latency -> 1x MFMA latency + 8 pk_adds. Costs only the
// second D tile (16 AGPRs); q/astat/E state unchanged -> no spill at cap 85.
__global__ __launch_bounds__(256, 6) void fused_kernel(const float* __restrict__ X,
                                                       float* __restrict__ ws,
                                                       float* __restrict__ out) {
  __shared__ __align__(16) ushort sh[LDS_TOT];
  __shared__ float msb[4];
  __shared__ int   peb[4];
  int tid = threadIdx.x;
  int l = tid & 63, w = tid >> 6;
  int n = l & 31, h = l >> 5;
  int tB = blockIdx.x << 7;
  int t0 = tB + (w << 5);
  int b  = t0 >> 12;
  if (blockIdx.x == 0 && tid == 0) *out = 0.0f;   // stream-ordered before combine

  // ---- stage WF table into LDS (once per block): 768 uint4 ----
  {
    const uint4* wfp = (const uint4*)((const ushort*)(ws + WS_WF));
    uint4* wfl = (uint4*)(sh + LDS_WF);
    #pragma unroll
    for (int k = 0; k < 3; ++k) wfl[tid + (k << 8)] = wfp[tid + (k << 8)];
  }
  float c0 = ws[WS_C0 + n];

  // ---- per-wave X slice staging: lane covers (row = l>>1, half sp = l&1) ----
  int srow = l >> 1, sp = l & 1;
  const float* xg = X + (size_t)(t0 + srow) * D_ + 8 * sp;
  ushort* xbuf = sh + LDS_WREG(w);        // first 768 ushorts of the wave region
  float2 va[4];
  auto xload = [&](int c) {
    #pragma unroll
    for (int s = 0; s < 4; ++s) {
      int d = 16 * c + 8 * sp + 2 * s;
      if (d < D_) va[s] = *(const float2*)(xg + 16 * c + 2 * s);
      else { va[s].x = 0.0f; va[s].y = 0.0f; }
    }
  };
  auto xwrite = [&]() {
    uint4 pkv;
    pkv.x = rnd_pk(va[0].y, va[0].x);
    pkv.y = rnd_pk(va[1].y, va[1].x);
    pkv.z = rnd_pk(va[2].y, va[2].x);
    pkv.w = rnd_pk(va[3].y, va[3].x);
    *(uint4*)(xbuf + srow * 24 + 8 * sp) = pkv;   // 16B-aligned (stride 48B)
  };
  xload(0);
  xwrite();          // slice 0 in LDS
  xload(1);          // slice 1 pending in regs
  __syncthreads();   // barrier#1: WF table ready

  // ---- emission: single accumulator, x*W1 + x^2*W2 ----
  const ushort* wfl = sh + LDS_WF;
  f32x16 acc;
  #pragma unroll
  for (int r = 0; r < 16; ++r) acc[r] = 0.0f;
  #pragma unroll
  for (int c = 0; c < 6; ++c) {
    union { uint4 u; bf16x8 v; } xb;
    xb.u = *(const uint4*)(xbuf + n * 24 + 8 * h);   // A-frag, slice c
    float x[8];
    #pragma unroll
    for (int j = 0; j < 8; ++j) {
      uint32_t uu = ((const uint32_t*)&xb.u)[j >> 1];
      x[j] = bf2f((j & 1) ? (ushort)(uu >> 16) : (ushort)(uu & 0xFFFF));
    }
    union { uint32_t u[4]; bf16x8 v; } x2b;
    #pragma unroll
    for (int r = 0; r < 4; ++r)
      x2b.u[r] = rnd_pk(x[2*r+1] * x[2*r+1], x[2*r] * x[2*r]);
    union { uint4 u; bf16x8 v; } w1, w2;
    w2.u = *(const uint4*)(wfl + (2 * c)     * 512 + l * 8);   // -0.5*iv
    w1.u = *(const uint4*)(wfl + (2 * c + 1) * 512 + l * 8);   // mu*iv
    acc = __builtin_amdgcn_mfma_f32_32x32x16_bf16(xb.v,  w1.v, acc, 0, 0, 0);
    acc = __builtin_amdgcn_mfma_f32_32x32x16_bf16(x2b.v, w2.v, acc, 0, 0, 0);
    if (c < 5) {
      xwrite();                 // write pending slice (DS order after read)
      if (c < 4) xload(c + 2);  // prefetch next into regs
    }
  }
  // C/D: col k = n, row t = (r&3) + 8*(r>>2) + 4*h
  float em[16], mrow[16];
  #pragma unroll
  for (int r = 0; r < 16; ++r) {
    float v = acc[r] + c0;
    em[r] = v;
    float m = v;
    #pragma unroll
    for (int mk = 1; mk <= 16; mk <<= 1) m = fmaxf(m, __shfl_xor(m, mk));  // max over k
    mrow[r] = m;
  }
  // E[k=n][t] tile, stride 40, overlays the (now dead) X buf of this wave.
  ushort* Ew = sh + LDS_WREG(w);
  #pragma unroll
  for (int q = 0; q < 4; ++q) {
    float e0 = exp2f((em[4*q]   - mrow[4*q])   * 1.44269504088896f);
    float e1 = exp2f((em[4*q+1] - mrow[4*q+1]) * 1.44269504088896f);
    float e2 = exp2f((em[4*q+2] - mrow[4*q+2]) * 1.44269504088896f);
    float e3 = exp2f((em[4*q+3] - mrow[4*q+3]) * 1.44269504088896f);
    uint2 d;
    d.x = rnd_pk(e1, e0);
    d.y = rnd_pk(e3, e2);
    *(uint2*)(Ew + n * 40 + 8 * q + 4 * h) = d;
    if (q == 0 && h == 0 && (t0 & (T_ - 1)) == 0)   // export E[b][k][0] for alpha0
      ((ushort*)(ws + WS_E0))[b * K_ + n] = (ushort)(d.x & 0xFFFF);
  }
  float msum = 0.0f;
  #pragma unroll
  for (int r = 0; r < 16; ++r) msum += mrow[r];
  msum += __shfl_xor(msum, 32);
  if (l == 0) msb[w] = msum;
  // no barrier: E tile is wave-private, in-wave lgkm ordering suffices

  // ---- chunk recursion (wave-local E from LDS) ----
  int col = perm_r(n);                    // logical output-state of this lane's A column
  const float* A = ws + WS_A;
  float astat[16];
  #pragma unroll
  for (int j = 0; j < 8; ++j) {
    astat[j]     = A[(8 * h + j) * K_ + col];
    astat[8 + j] = A[(16 + 8 * h + j) * K_ + col];
  }
  uint32_t q[8];                          // Q fragments (bf16x2 dwords), init = I
  #pragma unroll
  for (int r = 0; r < 4; ++r) {
    int s0 = 8 * h + 2 * r;
    uint32_t lo = (s0 == n)     ? 0x3F80u : 0u;
    uint32_t hi = (s0 + 1 == n) ? 0x3F80u : 0u;
    q[r] = lo | (hi << 16);
    int s2 = s0 + 16;
    lo = (s2 == n)     ? 0x3F80u : 0u;
    hi = (s2 + 1 == n) ? 0x3F80u : 0u;
    q[4 + r] = lo | (hi << 16);
  }
  int eacc = 0;
  const f32x16 z = {0.f,0.f,0.f,0.f,0.f,0.f,0.f,0.f,0.f,0.f,0.f,0.f,0.f,0.f,0.f,0.f};
  #pragma unroll
  for (int r = 0; r < 16; ++r) acc[r] = 0.0f;

  auto step = [&](float e0) {
    uint32_t au[8];
    #pragma unroll
    for (int r = 0; r < 4; ++r) {         // A-frag = astat * E[col], truncated bf16
      au[r]     = pk2(astat[2 * r + 1] * e0, astat[2 * r] * e0);
      au[4 + r] = pk2(astat[8 + 2 * r + 1] * e0, astat[8 + 2 * r] * e0);
    }
    bf16x8 alo = mkbf(au[0], au[1], au[2], au[3]);
    bf16x8 ahi = mkbf(au[4], au[5], au[6], au[7]);
    bf16x8 qlo = mkbf(q[0], q[1], q[2], q[3]);
    bf16x8 qhi = mkbf(q[4], q[5], q[6], q[7]);
    // INDEPENDENT MFMAs (both from zero), summed in VALU: halves the per-step
    // serial MFMA latency vs chaining the second through the C operand.
    f32x16 d1 = __builtin_amdgcn_mfma_f32_32x32x16_bf16(alo, qlo, z, 0, 0, 0);
    f32x16 d2 = __builtin_amdgcn_mfma_f32_32x32x16_bf16(ahi, qhi, z, 0, 0, 0);
    #pragma unroll
    for (int r = 0; r < 16; ++r) acc[r] = d1[r] + d2[r];
    #pragma unroll
    for (int r = 0; r < 4; ++r) {         // D regs -> next B-frag, in-lane repack
      q[r]     = pk2(acc[2 * r + 1], acc[2 * r]);
      q[4 + r] = pk2(acc[8 + 2 * r + 1], acc[8 + 2 * r]);
    }
  };
  auto lmul = [&](uint4 lo, uint4 hi) {   // left-multiply by a stored bf16 matrix
    bf16x8 alo = mkbf(lo.x, lo.y, lo.z, lo.w);
    bf16x8 ahi = mkbf(hi.x, hi.y, hi.z, hi.w);
    bf16x8 qlo = mkbf(q[0], q[1], q[2], q[3]);
    bf16x8 qhi = mkbf(q[4], q[5], q[6], q[7]);
    acc = __builtin_amdgcn_mfma_f32_32x32x16_bf16(alo, qlo, z, 0, 0, 0);
    acc = __builtin_amdgcn_mfma_f32_32x32x16_bf16(ahi, qhi, acc, 0, 0, 0);
    #pragma unroll
    for (int r = 0; r < 4; ++r) {
      q[r]     = pk2(acc[2 * r + 1], acc[2 * r]);
      q[4 + r] = pk2(acc[8 + 2 * r + 1], acc[8 + 2 * r]);
    }
  };
  auto renorm = [&]() {                   // exact power-of-2 renormalization
    float m = acc[0];
    #pragma unroll
    for (int r = 1; r < 16; ++r) m = fmaxf(m, acc[r]);
    #pragma unroll
    for (int mk = 1; mk <= 32; mk <<= 1) m = fmaxf(m, __shfl_xor(m, mk));
    int ex;
    frexpf(m, &ex);
    float sc = ldexpf(1.0f, -ex);
    eacc += ex;
    #pragma unroll
    for (int r = 0; r < 16; ++r) acc[r] *= sc;
    #pragma unroll
    for (int r = 0; r < 4; ++r) {
      q[r]     = pk2(acc[2 * r + 1], acc[2 * r]);
      q[4 + r] = pk2(acc[8 + 2 * r + 1], acc[8 + 2 * r]);
    }
  };

  const ushort* Eb = sh + LDS_WREG(w) + col * 40;
  int g0 = 0;
  if ((t0 & (T_ - 1)) == 0) {             // t=0 is the prior step: skip it
    uint4 ev = *(const uint4*)(Eb);
    #pragma unroll
    for (int j = 1; j < 8; ++j) {
      uint32_t u = ((const uint32_t*)&ev)[j >> 1];
      step(bf2f((j & 1) ? (ushort)(u >> 16) : (ushort)(u & 0xFFFF)));
    }
    renorm();
    g0 = 1;
  }
  for (int g = g0; g < CH_ / 8; ++g) {
    uint4 ev = *(const uint4*)(Eb + 8 * g);
    #pragma unroll
    for (int j = 0; j < 8; ++j) {
      uint32_t u = ((const uint32_t*)&ev)[j >> 1];
      step(bf2f((j & 1) ? (ushort)(u >> 16) : (ushort)(u & 0xFFFF)));
    }
    renorm();
  }

  // publish chunk product into own wave region (E fully consumed by this wave)
  ushort* Qw = sh + LDS_WREG(w);          // 32 rows x stride 40
  #pragma unroll
  for (int r = 0; r < 16; ++r) {          // row = pi(physical row), col = n
    int m_ = (r & 3) + 8 * (r >> 2) + 4 * h;
    Qw[perm_r(m_) * 40 + n] = (ushort)(__float_as_uint(acc[r]) >> 16);
  }
  if (l == 0) peb[w] = eacc;
  __syncthreads();                        // barrier#2: all Q products published
  if (w != 0) return;

  // ---- wave 0: compose the 4 chunk products (ascending = later on the left) ----
  #pragma unroll
  for (int r = 0; r < 4; ++r) {           // reset B-frag to identity
    int s0 = 8 * h + 2 * r;
    uint32_t lo = (s0 == n)     ? 0x3F80u : 0u;
    uint32_t hi = (s0 + 1 == n) ? 0x3F80u : 0u;
    q[r] = lo | (hi << 16);
    int s2 = s0 + 16;
    lo = (s2 == n)     ? 0x3F80u : 0u;
    hi = (s2 + 1 == n) ? 0x3F80u : 0u;
    q[4 + r] = lo | (hi << 16);
  }
  eacc = peb[0] + peb[1] + peb[2] + peb[3];
  float msm = msb[0] + msb[1] + msb[2] + msb[3];
  #pragma unroll
  for (int r = 0; r < 16; ++r) acc[r] = 0.0f;
  #pragma unroll
  for (int p = 0; p < 4; ++p) {
    const ushort* base = sh + LDS_WREG(p) + col * 40;  // col == perm_r(n) == A-frag row
    uint4 lo = *(const uint4*)(base + 8 * h);
    uint4 hi = *(const uint4*)(base + 16 + 8 * h);
    lmul(lo, hi);
  }
  renorm();
  ushort* Qo = (ushort*)(ws + WS_Q2) + (size_t)blockIdx.x * (K_ * K_);
  #pragma unroll
  for (int r = 0; r < 16; ++r) {
    int m_ = (r & 3) + 8 * (r >> 2) + 4 * h;
    Qo[perm_r(m_) * K_ + n] = (ushort)(__float_as_uint(acc[r]) >> 16);
  }
  if (l == 0) {
    ((int*)ws)[WS_EACC + blockIdx.x] = eacc;
    ws[WS_MS + blockIdx.x] = msm;
  }
}

// ---------------- combine: per b, compose 32 block products + alpha0 ----------------
__global__ __launch_bounds__(256) void combine_kernel(float* __restrict__ ws,
                                                      float* __restrict__ out) {
  __shared__ __align__(16) ushort pm[4][1280];   // stage-1 partials, stride 40
  __shared__ int pe[4];
  int tid = threadIdx.x;
  int l = tid & 63, w = tid >> 6;
  int h = l >> 5, n = l & 31;
  int b = blockIdx.x;
  int row = perm_r(n);
  int eacc;
  {
    const int* ea = ((const int*)ws) + WS_EACC + b * 32 + w * 8;
    int v = (l < 8) ? ea[l] : 0;
    #pragma unroll
    for (int mk = 1; mk <= 4; mk <<= 1) v += __shfl_xor(v, mk);
    eacc = __shfl(v, 0);
  }
  uint32_t q[8];                          // B-frag = identity
  #pragma unroll
  for (int r = 0; r < 4; ++r) {
    int s0 = 8 * h + 2 * r;
    uint32_t lo = (s0 == n)     ? 0x3F80u : 0u;
    uint32_t hi = (s0 + 1 == n) ? 0x3F80u : 0u;
    q[r] = lo | (hi << 16);
    int s2 = s0 + 16;
    lo = (s2 == n)     ? 0x3F80u : 0u;
    hi = (s2 + 1 == n) ? 0x3F80u : 0u;
    q[4 + r] = lo | (hi << 16);
  }
  f32x16 acc;
  #pragma unroll
  for (int r = 0; r < 16; ++r) acc[r] = 0.0f;
  const f32x16 z = {0.f,0.f,0.f,0.f,0.f,0.f,0.f,0.f,0.f,0.f,0.f,0.f,0.f,0.f,0.f,0.f};

  auto lmul = [&](uint4 lo, uint4 hi) {
    bf16x8 alo = mkbf(lo.x, lo.y, lo.z, lo.w);
    bf16x8 ahi = mkbf(hi.x, hi.y, hi.z, hi.w);
    bf16x8 qlo = mkbf(q[0], q[1], q[2], q[3]);
    bf16x8 qhi = mkbf(q[4], q[5], q[6], q[7]);
    acc = __builtin_amdgcn_mfma_f32_32x32x16_bf16(alo, qlo, z, 0, 0, 0);
    acc = __builtin_amdgcn_mfma_f32_32x32x16_bf16(ahi, qhi, acc, 0, 0, 0);
    #pragma unroll
    for (int r = 0; r < 4; ++r) {
      q[r]     = pk2(acc[2 * r + 1], acc[2 * r]);
      q[4 + r] = pk2(acc[8 + 2 * r + 1], acc[8 + 2 * r]);
    }
  };
  auto renorm = [&]() {
    float m = acc[0];
    #pragma unroll
    for (int r = 1; r < 16; ++r) m = fmaxf(m, acc[r]);
    #pragma unroll
    for (int mk = 1; mk <= 32; mk <<= 1) m = fmaxf(m, __shfl_xor(m, mk));
    int ex;
    frexpf(m, &ex);
    float sc = ldexpf(1.0f, -ex);
    eacc += ex;
    #pragma unroll
    for (int r = 0; r < 16; ++r) acc[r] *= sc;
    #pragma unroll
    for (int r = 0; r < 4; ++r) {
      q[r]     = pk2(acc[2 * r + 1], acc[2 * r]);
      q[4 + r] = pk2(acc[8 + 2 * r + 1], acc[8 + 2 * r]);
    }
  };

  // stage 1: wave w composes block products v = 8w .. 8w+7 (ascending)
  const ushort* Qb = (const ushort*)(ws + WS_Q2) + (size_t)(b * 32 + w * 8) * (K_ * K_);
  #pragma unroll
  for (int p = 0; p < 8; ++p) {
    const ushort* Mc = Qb + (size_t)p * (K_ * K_) + row * K_;
    uint4 lo = *(const uint4*)(Mc + 8 * h);
    uint4 hi = *(const uint4*)(Mc + 16 + 8 * h);
    lmul(lo, hi);
    if ((p & 3) == 3) renorm();
  }
  #pragma unroll
  for (int r = 0; r < 16; ++r) {
    int m_ = (r & 3) + 8 * (r >> 2) + 4 * h;
    pm[w][perm_r(m_) * 40 + n] = (ushort)(__float_as_uint(acc[r]) >> 16);
  }
  if (l == 0) pe[w] = eacc;
  __syncthreads();
  if (w != 0) return;

  // stage 2 (wave 0): compose 4 partials, apply alpha0, reduce, accumulate
  float alpha0 = ws[WS_PI + n] * bf2f(((const ushort*)(ws + WS_E0))[b * K_ + n]);
  float msm;
  {
    float v = (l < 32) ? ws[WS_MS + b * 32 + l] : 0.0f;
    #pragma unroll
    for (int mk = 1; mk <= 32; mk <<= 1) v += __shfl_xor(v, mk);
    msm = v;
  }
  #pragma unroll
  for (int r = 0; r < 4; ++r) {           // reset identity
    int s0 = 8 * h + 2 * r;
    uint32_t lo = (s0 == n)     ? 0x3F80u : 0u;
    uint32_t hi = (s0 + 1 == n) ? 0x3F80u : 0u;
    q[r] = lo | (hi << 16);
    int s2 = s0 + 16;
    lo = (s2 == n)     ? 0x3F80u : 0u;
    hi = (s2 + 1 == n) ? 0x3F80u : 0u;
    q[4 + r] = lo | (hi << 16);
  }
  #pragma unroll
  for (int r = 0; r < 16; ++r) acc[r] = 0.0f;
  int et = pe[0] + pe[1] + pe[2] + pe[3];
  #pragma unroll
  for (int p = 0; p < 4; ++p) {           // no renorm: entries bounded, fp32-safe
    const ushort* base = pm[p] + row * 40;
    uint4 lo = *(const uint4*)(base + 8 * h);
    uint4 hi = *(const uint4*)(base + 16 + 8 * h);
    lmul(lo, hi);
  }
  // ssum = sum_{k,j} Qtot[k][j] * alpha0[j]; lane holds col n, rows across (r,h)
  float part = 0.0f;
  #pragma unroll
  for (int r = 0; r < 16; ++r) part += acc[r];
  part *= alpha0;
  #pragma unroll
  for (int mk = 1; mk <= 32; mk <<= 1) part += __shfl_xor(part, mk);
  if (l == 0) {
    float res = logf(part) + (float)et * 0.69314718055994531f + msm;
    atomicAdd(out, res);
  }
}

extern "C" void kernel_launch(void* const* d_in, const int* in_sizes, int n_in,
                              void* d_out, int out_size, void* d_ws, size_t ws_size,
                              hipStream_t stream) {
  (void)in_sizes; (void)n_in; (void)out_size; (void)ws_size;
  const float* X      = (const float*)d_in[0];
  const float* priors = (const float*)d_in[1];
  const float* trans  = (const float*)d_in[2];
  const float* mu     = (const float*)d_in[3];
  const float* lv     = (const float*)d_in[4];
  float* ws  = (float*)d_ws;
  float* out = (float*)d_out;
  prep_kernel<<<1, 1024, 0, stream>>>(priors, trans, mu, lv, ws);
  fused_kernel<<<NB_, 256, 0, stream>>>(X, ws, out);
  combine_kernel<<<B_, 256, 0, stream>>>(ws, out);
}